// Round 7
// baseline (494.292 us; speedup 1.0000x reference)
//
#include <hip/hip_runtime.h>
#include <math.h>

// Problem constants
#define FD   256
#define NH   4
#define SP3  8
#define NP   32          // SP3*NH aux points per query
#define EDIM 64          // FD/NH
#define H    128
#define NS   1024
#define BS   4

#define TEX         (H*H)              // 16384 texels per (plane,b)
#define BATCH_ELEMS (TEX*FD)           // 4,194,304 floats
#define PAIR_B      2                  // batches processed per pass
#define PAIR_Q      (PAIR_B*NS)        // 2048 queries per pass
#define PPLANE      (PAIR_B*BATCH_ELEMS) // per-plane elems in pair buffer

// ---- workspace layout (float offsets). Total ~114.05 MB (layout kept from
// the proven rounds; feat/qk/aux/wf slots now unused after fusion).
#define WS_PLANES 0
#define WS_FEAT   (3*PPLANE)                       // [2048][256] (unused)
#define WS_QK     (WS_FEAT + PAIR_Q*FD)            // [2048][256] (unused)
#define WS_AUX    (WS_QK   + PAIR_Q*FD)            // [2048][96]  (unused)
#define WS_WF     (WS_AUX  + PAIR_Q*NP*3)          // [2048][4][256] (unused)
#define WS_PERM   (WS_WF   + PAIR_Q*NH*FD)         // [2 pairs][2048] uint

// bf16 helpers (round-to-nearest-even). Used ONLY on the wf path (af after
// the fp32 sim dot) — sim-path quantization is amplified ~176x and is fatal.
__device__ __forceinline__ unsigned short f2bf(float f) {
  unsigned b = __float_as_uint(f);
  return (unsigned short)((b + 0x7FFFu + ((b >> 16) & 1u)) >> 16);
}
__device__ __forceinline__ float bf2f(unsigned short u) {
  return __uint_as_float(((unsigned)u) << 16);
}

// ---------------------------------------------------------------------------
// K1: transpose planes [B,C,H,W] -> [b-pair][H*W,C] (channel-last).
// 32-texel x 256-channel tiles; LDS 33 KB -> 4 blocks/CU.
// ---------------------------------------------------------------------------
__global__ __launch_bounds__(256) void tpk2(
    const float* __restrict__ xz, const float* __restrict__ xy,
    const float* __restrict__ yz, float* __restrict__ dstAll, int b0)
{
  int bid = blockIdx.x;
  int tT = bid & 511; bid >>= 9;     // 512 texel-tiles of 32
  int bl = bid & 1;   bid >>= 1;     // local batch in pair
  int pl = bid;                      // plane
  const float* src = pl == 0 ? xz : (pl == 1 ? xy : yz);
  float* dst = dstAll + (size_t)pl * PPLANE + (size_t)bl * BATCH_ELEMS;
  int b = b0 + bl;

  __shared__ float T[32 * 260];      // T[texel][channel], stride 260
  int lane = threadIdx.x & 63, w = threadIdx.x >> 6;
  int tex4 = (lane & 7) * 4;         // 0,4,..,28
  int csub = lane >> 3;              // 0..7

  const float* sbase = src + (size_t)b * FD * TEX + tT * 32;
  #pragma unroll
  for (int i = 0; i < 8; i++) {
    int c = i * 32 + w * 8 + csub;   // covers 0..255
    float4 v = *(const float4*)(sbase + (size_t)c * TEX + tex4);
    T[(tex4 + 0) * 260 + c] = v.x;
    T[(tex4 + 1) * 260 + c] = v.y;
    T[(tex4 + 2) * 260 + c] = v.z;
    T[(tex4 + 3) * 260 + c] = v.w;
  }
  __syncthreads();
  #pragma unroll
  for (int i = 0; i < 8; i++) {
    int t = w * 8 + i;
    float4 v = *(const float4*)(&T[t * 260 + lane * 4]);
    *(float4*)(dst + (size_t)(tT * 32 + t) * FD + lane * 4) = v;  // 1KB/wave
  }
}

// ---------------------------------------------------------------------------
// K1b: counting-sort the pair's 2048 queries into 256 buckets =
// (batch<<7)|top-7-Morton-bits. One block per pair, O(n).
// ---------------------------------------------------------------------------
__device__ __forceinline__ unsigned mort7(unsigned v) {   // 7 bits -> every 3rd
  unsigned r = 0;
  #pragma unroll
  for (int i = 0; i < 7; i++) r |= ((v >> i) & 1u) << (3 * i);
  return r;
}

__global__ __launch_bounds__(1024) void sortk(
    const float* __restrict__ qpos, unsigned* __restrict__ perm)
{
  const int pair = blockIdx.x;
  const int b0 = pair * PAIR_B;
  const int t = threadIdx.x;
  __shared__ unsigned cnt[256];
  __shared__ unsigned base[256];
  if (t < 256) cnt[t] = 0;
  __syncthreads();
  unsigned myb[2];
  #pragma unroll
  for (int r = 0; r < 2; r++) {
    int i = t + r * 1024;
    size_t qg = (size_t)b0 * NS + i;
    float x = fminf(fmaxf(qpos[qg * 3 + 0], 0.f), 1.f);
    float y = fminf(fmaxf(qpos[qg * 3 + 1], 0.f), 1.f);
    float z = fminf(fmaxf(qpos[qg * 3 + 2], 0.f), 1.f);
    unsigned m = (mort7((unsigned)(x * 127.f)) << 2)
               | (mort7((unsigned)(y * 127.f)) << 1)
               |  mort7((unsigned)(z * 127.f));          // 21 bits
    unsigned bkt = ((unsigned)(i >> 10) << 7) | (m >> 14);
    myb[r] = bkt;
    atomicAdd(&cnt[bkt], 1u);
  }
  __syncthreads();
  if (t == 0) {
    unsigned s = 0;
    for (int k = 0; k < 256; k++) { base[k] = s; s += cnt[k]; }
  }
  __syncthreads();
  #pragma unroll
  for (int r = 0; r < 2; r++) {
    int i = t + r * 1024;
    unsigned pos = atomicAdd(&base[myb[r]], 1u);
    perm[(size_t)pair * PAIR_Q + pos] = (unsigned)i;
  }
}

// ---------------------------------------------------------------------------
// Bilinear helpers (channel-last plane)
// ---------------------------------------------------------------------------
__device__ __forceinline__ float sample_plane(const float* __restrict__ p,
                                              float u, float v) {
  float x = fminf(fmaxf(u, 0.f), 1.f) * (float)(H - 1);
  float y = fminf(fmaxf(v, 0.f), 1.f) * (float)(H - 1);
  float xf = floorf(x), yf = floorf(y);
  int x0 = (int)xf, y0 = (int)yf;
  float wx = x - xf, wy = y - yf;
  int dx = (x0 < H - 1) ? FD : 0;
  int dy = (y0 < H - 1) ? H * FD : 0;
  int i00 = (y0 * H + x0) * FD;
  float f00 = p[i00], f01 = p[i00 + dx], f10 = p[i00 + dy], f11 = p[i00 + dy + dx];
  float a = f00 + wx * (f01 - f00);
  float b = f10 + wx * (f11 - f10);
  return a + wy * (b - a);
}

__device__ __forceinline__ void setup_samp(int* si, float* sw, float u, float v) {
  float x = fminf(fmaxf(u, 0.f), 1.f) * (float)(H - 1);
  float y = fminf(fmaxf(v, 0.f), 1.f) * (float)(H - 1);
  float xf = floorf(x), yf = floorf(y);
  int x0 = (int)xf, y0 = (int)yf;
  float wx = x - xf, wy = y - yf;
  si[0] = (y0 * H + x0) * FD;
  si[1] = (x0 < H - 1) ? FD : 0;
  si[2] = (y0 < H - 1) ? H * FD : 0;
  sw[0] = (1.f - wy) * (1.f - wx);
  sw[1] = (1.f - wy) * wx;
  sw[2] = wy * (1.f - wx);
  sw[3] = wy * wx;
}

// ---------------------------------------------------------------------------
// K3 (FUSED, hot): one query per block; featk + attnk + epik in one kernel.
// ROUND-7 CHANGE: r5/r6 showed the compiler SINKS the prefetch loads down to
// their consumers (VGPR 32/44 instead of ~100; fetch rate 2.2 TB/s vs the
// 3.45 TB/s wall r4 hit) — named buffers alone don't survive the scheduler.
// Fix: __builtin_amdgcn_sched_barrier(0) after every issue-group pins the
// loads above the subsequent consumes (nothing may cross the barrier), so
// the compiler must keep buffers live and emit counted vmcnt. Pipeline:
// groups of 2 quads (8 loads), 2 groups in flight -> 16 loads/wave
// outstanding; 16 waves/CU x 16 >> the ~60 lines/CU the 3.45 TB/s wall
// needs. Tripwire: if VGPR stays ~44 the barrier failed too -> inline asm.
// FP accumulation orders unchanged everywhere (absmax must stay 0.1279297).
// ---------------------------------------------------------------------------
__global__ __launch_bounds__(256, 4) void fusedk(
    const float* __restrict__ qpos, const float* __restrict__ planesT,
    const float* __restrict__ w_off, const float* __restrict__ b_off,
    const float* __restrict__ w_q, const float* __restrict__ b_q,
    const float* __restrict__ w_k,
    const float* __restrict__ w_v, const float* __restrict__ b_v,
    const float* __restrict__ w_out, const float* __restrict__ b_out,
    const unsigned* __restrict__ perm, float* __restrict__ out, int b0)
{
  const int tid = threadIdx.x, lane = tid & 63, w = tid >> 6;
  const int bid = blockIdx.x;                 // 0..2047
  const int j = ((bid & 7) << 8) | (bid >> 3);  // XCD-chunked swizzle
  const int c4 = lane * 4;

  __shared__ float s_feat[FD];        // 1 KB   (query feature; lives to stage5)
  __shared__ float s_aux[96];         // aux coords
  __shared__ float s_q[EDIM];         // scaled q
  __shared__ float s_qk[FD];          // qk row
  __shared__ int   s_si[96][3];
  __shared__ float s_sw[96][4];
  __shared__ float s_wf[NH * FD];     // 4 KB   (per-head attn output)
  __shared__ float s_o[FD];           // o = concat-head @ w_v

  const int qw = (int)perm[j];                // this block's query (uniform)
  const int blw = qw >> 10;
  const size_t qg = (size_t)b0 * NS + qw;     // global query row
  const float px = qpos[qg * 3 + 0];
  const float py = qpos[qg * 3 + 1];
  const float pz = qpos[qg * 3 + 2];

  const float* Pxz = planesT + 0 * (size_t)PPLANE + (size_t)blw * BATCH_ELEMS;
  const float* Pxy = planesT + 1 * (size_t)PPLANE + (size_t)blw * BATCH_ELEMS;
  const float* Pyz = planesT + 2 * (size_t)PPLANE + (size_t)blw * BATCH_ELEMS;

  // ---- stage 1: feature at query pos (thread = channel; same op order as featk)
  {
    float f = sample_plane(Pxz + tid, px, pz) + sample_plane(Pxy + tid, px, py)
            + sample_plane(Pyz + tid, py, pz);
    s_feat[tid] = f;
  }
  __syncthreads();

  // ---- stage 2: unified 256-dot. Uniform loop body (no divergence inside),
  // divergent only in base pointer/stride/bias.
  if (tid < 160) {
    const bool isOff = tid < 96;
    const int  col   = isOff ? tid : (tid - 96);
    const float* Wp  = isOff ? (w_off + col) : (w_q + col);
    const int  strd  = isOff ? 96 : EDIM;
    float acc = isOff ? b_off[col] : b_q[col];
    for (int c = 0; c < FD; c++) {
      acc = fmaf(s_feat[c], *Wp, acc);
      Wp += strd;
    }
    if (isOff) {
      int d = col % 3;
      float qp = (d == 0) ? px : ((d == 1) ? py : pz);
      s_aux[col] = acc + qp;
    } else {
      s_q[col] = acc * 8.0f;          // scaled by sqrt(E)=8 (b_k cancels)
    }
  }
  __syncthreads();

  // ---- stage 3: qk[c] (all 256 threads) + setup_samp (tid<96)
  {
    float acc = 0.f;
    const float* wk = w_k + (size_t)tid * EDIM;
    for (int e = 0; e < EDIM; e++)
      acc = fmaf(s_q[e], wk[e], acc);  // e ascending == featk's float4 order
    s_qk[tid] = acc;
  }
  if (tid < 96) {
    int p = tid / 3, pl = tid - p * 3;
    float ax = s_aux[p * 3 + 0];
    float ay = s_aux[p * 3 + 1];
    float az = s_aux[p * 3 + 2];
    float u = (pl == 2) ? ay : ax;   // pl0:(ax,az) pl1:(ax,ay) pl2:(ay,az)
    float v = (pl == 1) ? ay : az;
    setup_samp(s_si[tid], s_sw[tid], u, v);
  }
  __syncthreads();

  // ---- stage 4: sched_barrier-pinned pipelined gather + wave-uniform softmax.
  const int h = w;                            // wave = head
  float4 qk4 = *(const float4*)(s_qk + c4);
  const float* P0 = Pxz + c4;
  const float* P1 = Pxy + c4;
  const float* P2 = Pyz + c4;

  ushort4 af16[SP3];                          // bf16 af (static idx)
  float t[SP3];                               // per-lane sim partials
  float4 acc;                                 // current point's af accumulator

  // two groups of 2 quads, 8 float4 each -> 16 loads in flight
  float4 a0,a1,a2,a3,a4,a5,a6,a7;             // group A
  float4 g0,g1,g2,g3,g4,g5,g6,g7;             // group B

  auto issue = [&](int k, float4& b00, float4& b01, float4& b10, float4& b11) {
    const int pl = k % 3;
    const int p  = (k / 3) * NH + h;
    const float* P = pl == 0 ? P0 : (pl == 1 ? P1 : P2);
    int i00 = s_si[p * 3 + pl][0];
    int dxo = s_si[p * 3 + pl][1];
    int dyo = s_si[p * 3 + pl][2];
    b00 = *(const float4*)(P + i00);
    b01 = *(const float4*)(P + i00 + dxo);
    b10 = *(const float4*)(P + i00 + dyo);
    b11 = *(const float4*)(P + i00 + dyo + dxo);
  };
  auto consume = [&](int k, float4& b00, float4& b01, float4& b10, float4& b11) {
    const int pl = k % 3, jj = k / 3;
    const int p  = jj * NH + h;
    float w0 = s_sw[p * 3 + pl][0], w1 = s_sw[p * 3 + pl][1];
    float w2 = s_sw[p * 3 + pl][2], w3 = s_sw[p * 3 + pl][3];
    if (pl == 0) { acc.x = 0.f; acc.y = 0.f; acc.z = 0.f; acc.w = 0.f; }
    acc.x = fmaf(w0, b00.x, fmaf(w1, b01.x, fmaf(w2, b10.x, fmaf(w3, b11.x, acc.x))));
    acc.y = fmaf(w0, b00.y, fmaf(w1, b01.y, fmaf(w2, b10.y, fmaf(w3, b11.y, acc.y))));
    acc.z = fmaf(w0, b00.z, fmaf(w1, b01.z, fmaf(w2, b10.z, fmaf(w3, b11.z, acc.z))));
    acc.w = fmaf(w0, b00.w, fmaf(w1, b01.w, fmaf(w2, b10.w, fmaf(w3, b11.w, acc.w))));
    if (pl == 2) {
      ushort4 hh;
      hh.x = f2bf(acc.x); hh.y = f2bf(acc.y); hh.z = f2bf(acc.z); hh.w = f2bf(acc.w);
      af16[jj] = hh;
      t[jj] = fmaf(qk4.x, acc.x, fmaf(qk4.y, acc.y, fmaf(qk4.z, acc.z, qk4.w * acc.w)));
    }
  };

  // ISSUE2: issue 2 quads then PIN them above everything that follows.
#define ISSUE2(k, X0,X1,X2,X3,X4,X5,X6,X7) \
    issue((k), X0, X1, X2, X3);            \
    issue((k)+1, X4, X5, X6, X7);          \
    __builtin_amdgcn_sched_barrier(0);
#define CONS2(k, X0,X1,X2,X3,X4,X5,X6,X7)  \
    consume((k), X0, X1, X2, X3);          \
    consume((k)+1, X4, X5, X6, X7);

  ISSUE2(0,  a0,a1,a2,a3,a4,a5,a6,a7)
  ISSUE2(2,  g0,g1,g2,g3,g4,g5,g6,g7)
  CONS2 (0,  a0,a1,a2,a3,a4,a5,a6,a7)
  ISSUE2(4,  a0,a1,a2,a3,a4,a5,a6,a7)
  CONS2 (2,  g0,g1,g2,g3,g4,g5,g6,g7)
  ISSUE2(6,  g0,g1,g2,g3,g4,g5,g6,g7)
  CONS2 (4,  a0,a1,a2,a3,a4,a5,a6,a7)
  ISSUE2(8,  a0,a1,a2,a3,a4,a5,a6,a7)
  CONS2 (6,  g0,g1,g2,g3,g4,g5,g6,g7)
  ISSUE2(10, g0,g1,g2,g3,g4,g5,g6,g7)
  CONS2 (8,  a0,a1,a2,a3,a4,a5,a6,a7)
  ISSUE2(12, a0,a1,a2,a3,a4,a5,a6,a7)
  CONS2 (10, g0,g1,g2,g3,g4,g5,g6,g7)
  ISSUE2(14, g0,g1,g2,g3,g4,g5,g6,g7)
  CONS2 (12, a0,a1,a2,a3,a4,a5,a6,a7)
  ISSUE2(16, a0,a1,a2,a3,a4,a5,a6,a7)
  CONS2 (14, g0,g1,g2,g3,g4,g5,g6,g7)
  ISSUE2(18, g0,g1,g2,g3,g4,g5,g6,g7)
  CONS2 (16, a0,a1,a2,a3,a4,a5,a6,a7)
  ISSUE2(20, a0,a1,a2,a3,a4,a5,a6,a7)
  CONS2 (18, g0,g1,g2,g3,g4,g5,g6,g7)
  ISSUE2(22, g0,g1,g2,g3,g4,g5,g6,g7)
  CONS2 (20, a0,a1,a2,a3,a4,a5,a6,a7)
  CONS2 (22, g0,g1,g2,g3,g4,g5,g6,g7)
#undef ISSUE2
#undef CONS2

  #pragma unroll
  for (int o = 32; o >= 1; o >>= 1) {
    #pragma unroll
    for (int jj = 0; jj < SP3; jj++) t[jj] += __shfl_xor(t[jj], o, 64);
  }

  float m = -1e30f;
  #pragma unroll
  for (int jj = 0; jj < SP3; jj++) m = fmaxf(m, t[jj]);
  float sum = 0.f;
  #pragma unroll
  for (int jj = 0; jj < SP3; jj++) { t[jj] = __expf(t[jj] - m); sum += t[jj]; }
  float inv = 1.0f / sum;
  float4 r; r.x = 0.f; r.y = 0.f; r.z = 0.f; r.w = 0.f;
  #pragma unroll
  for (int jj = 0; jj < SP3; jj++) {
    float av = t[jj] * inv;
    ushort4 hv = af16[jj];
    r.x = fmaf(av, bf2f(hv.x), r.x);
    r.y = fmaf(av, bf2f(hv.y), r.y);
    r.z = fmaf(av, bf2f(hv.z), r.z);
    r.w = fmaf(av, bf2f(hv.w), r.w);
  }
  *(float4*)(s_wf + h * FD + c4) = r;         // was the wf global write
  __syncthreads();

  // ---- stage 5A: o[h*64+e] = b_v[e] + sum_c wf[h][c] * w_v[c][e]
  {
    const int hh = tid >> 6, e = tid & 63;
    float a5 = b_v[e];
    const float* wrow = s_wf + hh * FD;
    for (int c = 0; c < FD; c++)
      a5 = fmaf(wrow[c], w_v[(size_t)c * EDIM + e], a5);  // epik phase-A order
    s_o[tid] = a5;                            // tid == hh*EDIM+e
  }
  __syncthreads();

  // ---- stage 5B: out[d] = b_out[d] + sum_c o[c]*w_out[c][d] + feat[d]
  {
    float r5 = b_out[tid];
    for (int c = 0; c < FD; c++)
      r5 = fmaf(s_o[c], w_out[(size_t)c * FD + tid], r5);  // epik phase-B order
    out[qg * FD + tid] = r5 + s_feat[tid];
  }
}

// ---------------------------------------------------------------------------
extern "C" void kernel_launch(void* const* d_in, const int* in_sizes, int n_in,
                              void* d_out, int out_size, void* d_ws, size_t ws_size,
                              hipStream_t stream) {
  const float* qp    = (const float*)d_in[0];
  const float* cxz   = (const float*)d_in[1];
  const float* cxy   = (const float*)d_in[2];
  const float* cyz   = (const float*)d_in[3];
  const float* w_off = (const float*)d_in[4];
  const float* b_off = (const float*)d_in[5];
  const float* w_q   = (const float*)d_in[6];
  const float* b_q   = (const float*)d_in[7];
  const float* w_k   = (const float*)d_in[8];
  const float* b_k   = (const float*)d_in[9];   (void)b_k; // cancels in softmax
  const float* w_v   = (const float*)d_in[10];
  const float* b_v   = (const float*)d_in[11];
  const float* w_out = (const float*)d_in[12];
  const float* b_out = (const float*)d_in[13];
  float* out = (float*)d_out;
  (void)in_sizes; (void)n_in; (void)out_size; (void)ws_size;

  float* ws      = (float*)d_ws;
  float* planesT = ws + WS_PLANES;
  unsigned* perm = (unsigned*)(ws + WS_PERM);

  hipLaunchKernelGGL(sortk, dim3(BS / PAIR_B), dim3(1024), 0, stream, qp, perm);

  for (int pair = 0; pair < BS / PAIR_B; ++pair) {
    int b0 = pair * PAIR_B;
    hipLaunchKernelGGL(tpk2, dim3(3 * PAIR_B * 512), dim3(256), 0, stream,
                       cxz, cxy, cyz, planesT, b0);
    hipLaunchKernelGGL(fusedk, dim3(PAIR_Q), dim3(256), 0, stream,
                       qp, planesT, w_off, b_off, w_q, b_q, w_k,
                       w_v, b_v, w_out, b_out,
                       perm + (size_t)pair * PAIR_Q, out, b0);
  }
}